// Round 1
// baseline (101.648 us; speedup 1.0000x reference)
//
#include <hip/hip_runtime.h>

// MedianBlur 3x3, zero padding, fp32, image (16,3,512,512).
// Strategy: memory-bound kernel (~100 MB total traffic -> ~16 us floor).
// Each thread computes a 4-wide x 8-tall output strip:
//   - per input row: one aligned float4 load + 2 scalar halo loads (cols x0-1, x0+4)
//   - 3 rows rolled in registers
//   - median-of-9 via column-sort identity:
//       sort each 3-col vertically (v_min3/v_med3/v_max3),
//       median9 = med3( max3(mins), med3(meds), min3(maxes) )
//     ~8.5 VALU ops per output.
// Stores: one float4 per output row per thread (fully coalesced).

#define MB_W 512
#define MB_H 512
#define MB_R 8   // rows per thread

__device__ __forceinline__ float min3f(float a, float b, float c) {
    return fminf(fminf(a, b), c);
}
__device__ __forceinline__ float max3f(float a, float b, float c) {
    return fmaxf(fmaxf(a, b), c);
}
__device__ __forceinline__ float med3f(float a, float b, float c) {
    return __builtin_amdgcn_fmed3f(a, b, c);
}

__global__ __launch_bounds__(256) void median3x3_kernel(
    const float* __restrict__ in, float* __restrict__ out) {
    const int W = MB_W, H = MB_H;
    const int tid = blockIdx.x * blockDim.x + threadIdx.x;

    // 128 column-groups (4 cols each), 64 row-groups (8 rows each), per plane.
    const int xg    = tid & 127;
    const int yg    = (tid >> 7) & 63;
    const int plane = tid >> 13;          // 48 planes total

    const int x0 = xg << 2;               // first of 4 output columns
    const int y0 = yg << 3;               // first of 8 output rows

    const float* __restrict__ p = in  + (size_t)plane * (H * W);
    float*       __restrict__ q = out + (size_t)plane * (H * W);

    float r0[6], r1[6], r2[6];            // rolling rows: cols x0-1 .. x0+4

    auto loadrow = [&](int y, float* r) {
        if (y < 0 || y >= H) {
            #pragma unroll
            for (int j = 0; j < 6; ++j) r[j] = 0.f;
            return;
        }
        const float* rp = p + y * W + x0;
        const float4 v = *(const float4*)rp;   // 16B aligned (x0 % 4 == 0)
        r[1] = v.x; r[2] = v.y; r[3] = v.z; r[4] = v.w;
        r[0] = (x0 > 0)     ? rp[-1] : 0.f;    // left halo (zero pad)
        r[5] = (x0 + 4 < W) ? rp[4]  : 0.f;    // right halo (zero pad)
    };

    loadrow(y0 - 1, r0);
    loadrow(y0,     r1);

    #pragma unroll
    for (int k = 0; k < MB_R; ++k) {
        const int y = y0 + k;
        loadrow(y + 1, r2);

        float lo[6], md[6], hi[6];
        #pragma unroll
        for (int j = 0; j < 6; ++j) {
            const float a = r0[j], b = r1[j], c = r2[j];
            lo[j] = min3f(a, b, c);
            md[j] = med3f(a, b, c);
            hi[j] = max3f(a, b, c);
        }

        float4 o;
        float* po = &o.x;
        #pragma unroll
        for (int i = 0; i < 4; ++i) {
            const float mx = max3f(lo[i], lo[i + 1], lo[i + 2]);
            const float mm = med3f(md[i], md[i + 1], md[i + 2]);
            const float mn = min3f(hi[i], hi[i + 1], hi[i + 2]);
            po[i] = med3f(mx, mm, mn);
        }
        *(float4*)(q + y * W + x0) = o;

        #pragma unroll
        for (int j = 0; j < 6; ++j) { r0[j] = r1[j]; r1[j] = r2[j]; }
    }
}

extern "C" void kernel_launch(void* const* d_in, const int* in_sizes, int n_in,
                              void* d_out, int out_size, void* d_ws, size_t ws_size,
                              hipStream_t stream) {
    const float* in = (const float*)d_in[0];
    float* out = (float*)d_out;
    // 16*3 planes * 64 row-groups * 128 col-groups = 393216 threads
    const int total_threads = 48 * 64 * 128;
    const int block = 256;
    const int grid = total_threads / block;   // 1536 blocks
    median3x3_kernel<<<grid, block, 0, stream>>>(in, out);
}

// Round 3
// 99.033 us; speedup vs baseline: 1.0264x; 1.0264x over previous
//
#include <hip/hip_runtime.h>

// MedianBlur 3x3, zero padding, fp32, (16,3,512,512).
// R3: same as R2 but with clang native ext-vector type so
// __builtin_nontemporal_store compiles (HIP float4 is a class type).
//   - 10 row loads per thread (dwordx4, coalesced, hoisted for MLP)
//   - horizontal halos via __shfl_up/__shfl_down; lanes 0/63 fix-up loads
//   - median-of-9 via column-sort identity (v_min3/v_med3/v_max3)
//   - nontemporal dwordx4 stores

#define MB_W 512
#define MB_H 512
#define MB_R 8   // output rows per thread

typedef float vf4 __attribute__((ext_vector_type(4)));

__device__ __forceinline__ float min3f(float a, float b, float c) {
    return fminf(fminf(a, b), c);
}
__device__ __forceinline__ float max3f(float a, float b, float c) {
    return fmaxf(fmaxf(a, b), c);
}
__device__ __forceinline__ float med3f(float a, float b, float c) {
    return __builtin_amdgcn_fmed3f(a, b, c);
}

__global__ __launch_bounds__(256) void median3x3_kernel(
    const float* __restrict__ in, float* __restrict__ out) {
    const int W = MB_W, H = MB_H;
    const int tid  = blockIdx.x * blockDim.x + threadIdx.x;
    const int lane = threadIdx.x & 63;

    // 128 col-groups (4 cols), 64 row-groups (8 rows), 48 planes.
    // Wave lanes 0..63 map to consecutive xg — same yg/plane per wave.
    const int xg    = tid & 127;
    const int yg    = (tid >> 7) & 63;
    const int plane = tid >> 13;

    const int x0 = xg << 2;
    const int y0 = yg << 3;

    const float* __restrict__ p = in  + (size_t)plane * (H * W);
    float*       __restrict__ q = out + (size_t)plane * (H * W);

    // ---- Load 10 rows (y0-1 .. y0+8) as dwordx4; boundary rows zero ----
    vf4 v[MB_R + 2];
    #pragma unroll
    for (int r = 0; r < MB_R + 2; ++r) {
        const int y = y0 - 1 + r;
        if (y >= 0 && y < H) {                 // wave-uniform branch
            v[r] = *(const vf4*)(p + y * W + x0);
        } else {
            v[r] = (vf4){0.f, 0.f, 0.f, 0.f};
        }
    }

    // ---- Horizontal halos via cross-lane shuffle ----
    float lft[MB_R + 2], rgt[MB_R + 2];
    #pragma unroll
    for (int r = 0; r < MB_R + 2; ++r) {
        lft[r] = __shfl_up(v[r].w, 1);         // lane i-1's col x0-1
        rgt[r] = __shfl_down(v[r].x, 1);       // lane i+1's col x0+4
    }
    // Fix-up wave-edge lanes (1 active lane -> 1 cache line each).
    if (lane == 0) {
        #pragma unroll
        for (int r = 0; r < MB_R + 2; ++r) {
            const int y = y0 - 1 + r;
            lft[r] = (x0 > 0 && y >= 0 && y < H) ? p[y * W + x0 - 1] : 0.f;
        }
    }
    if (lane == 63) {
        #pragma unroll
        for (int r = 0; r < MB_R + 2; ++r) {
            const int y = y0 - 1 + r;
            rgt[r] = (x0 + 4 < W && y >= 0 && y < H) ? p[y * W + x0 + 4] : 0.f;
        }
    }

    // ---- Median-of-9 per output row ----
    #pragma unroll
    for (int k = 0; k < MB_R; ++k) {
        const float a0[6] = {lft[k],     v[k].x,     v[k].y,     v[k].z,     v[k].w,     rgt[k]};
        const float a1[6] = {lft[k + 1], v[k + 1].x, v[k + 1].y, v[k + 1].z, v[k + 1].w, rgt[k + 1]};
        const float a2[6] = {lft[k + 2], v[k + 2].x, v[k + 2].y, v[k + 2].z, v[k + 2].w, rgt[k + 2]};

        float lo[6], md[6], hi[6];
        #pragma unroll
        for (int j = 0; j < 6; ++j) {
            lo[j] = min3f(a0[j], a1[j], a2[j]);
            md[j] = med3f(a0[j], a1[j], a2[j]);
            hi[j] = max3f(a0[j], a1[j], a2[j]);
        }

        vf4 o;
        #pragma unroll
        for (int i = 0; i < 4; ++i) {
            const float mx = max3f(lo[i], lo[i + 1], lo[i + 2]);
            const float mm = med3f(md[i], md[i + 1], md[i + 2]);
            const float mn = min3f(hi[i], hi[i + 1], hi[i + 2]);
            o[i] = med3f(mx, mm, mn);
        }
        __builtin_nontemporal_store(o, (vf4*)(q + (y0 + k) * W + x0));
    }
}

extern "C" void kernel_launch(void* const* d_in, const int* in_sizes, int n_in,
                              void* d_out, int out_size, void* d_ws, size_t ws_size,
                              hipStream_t stream) {
    const float* in = (const float*)d_in[0];
    float* out = (float*)d_out;
    const int total_threads = 48 * 64 * 128;   // planes * ygroups * xgroups
    const int block = 256;
    const int grid = total_threads / block;    // 1536 blocks
    median3x3_kernel<<<grid, block, 0, stream>>>(in, out);
}

// Round 4
// 95.745 us; speedup vs baseline: 1.0616x; 1.0343x over previous
//
#include <hip/hip_runtime.h>

// MedianBlur 3x3, zero padding, fp32, (16,3,512,512).
// R4: R3 + (a) 16 output rows/thread (vertical halo over-fetch 1.25x -> 1.125x)
//        + (b) XCD-aware block swizzle: HW assigns XCD = blockIdx % 8; remap so
//          each XCD owns 3 whole planes (1 MB/plane fits its 4 MB L2) -> all
//          vertical-halo re-reads are L2-local instead of cross-XCD L3.
//   - 18 row loads per thread (dwordx4, coalesced, hoisted for MLP)
//   - horizontal halos via __shfl_up/__shfl_down; lanes 0/63 fix-up loads
//   - median-of-9 via column-sort identity (v_min3/v_med3/v_max3)
//   - nontemporal dwordx4 stores (output never re-read)

#define MB_W 512
#define MB_H 512
#define MB_R 16   // output rows per thread

typedef float vf4 __attribute__((ext_vector_type(4)));

__device__ __forceinline__ float min3f(float a, float b, float c) {
    return fminf(fminf(a, b), c);
}
__device__ __forceinline__ float max3f(float a, float b, float c) {
    return fmaxf(fmaxf(a, b), c);
}
__device__ __forceinline__ float med3f(float a, float b, float c) {
    return __builtin_amdgcn_fmed3f(a, b, c);
}

__global__ __launch_bounds__(256) void median3x3_kernel(
    const float* __restrict__ in, float* __restrict__ out) {
    const int W = MB_W, H = MB_H;
    const int lane = threadIdx.x & 63;

    // XCD swizzle: 768 blocks, 8 XCDs round-robin on blockIdx%8.
    // logical = (blockIdx%8)*96 + blockIdx/8  -> XCD k owns logical [96k,96k+96)
    // = 3 consecutive planes (32 blocks/plane).
    const int nb     = gridDim.x;              // 768
    const int chunk  = nb >> 3;                // 96
    const int logical = (blockIdx.x & 7) * chunk + (blockIdx.x >> 3);
    const int tid = logical * blockDim.x + threadIdx.x;

    // 128 col-groups (4 cols), 32 row-groups (16 rows), 48 planes.
    const int xg    = tid & 127;
    const int yg    = (tid >> 7) & 31;
    const int plane = tid >> 12;

    const int x0 = xg << 2;
    const int y0 = yg << 4;

    const float* __restrict__ p = in  + (size_t)plane * (H * W);
    float*       __restrict__ q = out + (size_t)plane * (H * W);

    // ---- Load 18 rows (y0-1 .. y0+16) as dwordx4; boundary rows zero ----
    vf4 v[MB_R + 2];
    #pragma unroll
    for (int r = 0; r < MB_R + 2; ++r) {
        const int y = y0 - 1 + r;
        if (y >= 0 && y < H) {                 // wave-uniform branch
            v[r] = *(const vf4*)(p + y * W + x0);
        } else {
            v[r] = (vf4){0.f, 0.f, 0.f, 0.f};
        }
    }

    // ---- Horizontal halos via cross-lane shuffle ----
    float lft[MB_R + 2], rgt[MB_R + 2];
    #pragma unroll
    for (int r = 0; r < MB_R + 2; ++r) {
        lft[r] = __shfl_up(v[r].w, 1);         // lane i-1's col x0-1
        rgt[r] = __shfl_down(v[r].x, 1);       // lane i+1's col x0+4
    }
    // Fix-up wave-edge lanes (1 active lane -> 1 cache line each).
    if (lane == 0) {
        #pragma unroll
        for (int r = 0; r < MB_R + 2; ++r) {
            const int y = y0 - 1 + r;
            lft[r] = (x0 > 0 && y >= 0 && y < H) ? p[y * W + x0 - 1] : 0.f;
        }
    }
    if (lane == 63) {
        #pragma unroll
        for (int r = 0; r < MB_R + 2; ++r) {
            const int y = y0 - 1 + r;
            rgt[r] = (x0 + 4 < W && y >= 0 && y < H) ? p[y * W + x0 + 4] : 0.f;
        }
    }

    // ---- Median-of-9 per output row ----
    #pragma unroll
    for (int k = 0; k < MB_R; ++k) {
        const float a0[6] = {lft[k],     v[k].x,     v[k].y,     v[k].z,     v[k].w,     rgt[k]};
        const float a1[6] = {lft[k + 1], v[k + 1].x, v[k + 1].y, v[k + 1].z, v[k + 1].w, rgt[k + 1]};
        const float a2[6] = {lft[k + 2], v[k + 2].x, v[k + 2].y, v[k + 2].z, v[k + 2].w, rgt[k + 2]};

        float lo[6], md[6], hi[6];
        #pragma unroll
        for (int j = 0; j < 6; ++j) {
            lo[j] = min3f(a0[j], a1[j], a2[j]);
            md[j] = med3f(a0[j], a1[j], a2[j]);
            hi[j] = max3f(a0[j], a1[j], a2[j]);
        }

        vf4 o;
        #pragma unroll
        for (int i = 0; i < 4; ++i) {
            const float mx = max3f(lo[i], lo[i + 1], lo[i + 2]);
            const float mm = med3f(md[i], md[i + 1], md[i + 2]);
            const float mn = min3f(hi[i], hi[i + 1], hi[i + 2]);
            o[i] = med3f(mx, mm, mn);
        }
        __builtin_nontemporal_store(o, (vf4*)(q + (y0 + k) * W + x0));
    }
}

extern "C" void kernel_launch(void* const* d_in, const int* in_sizes, int n_in,
                              void* d_out, int out_size, void* d_ws, size_t ws_size,
                              hipStream_t stream) {
    const float* in = (const float*)d_in[0];
    float* out = (float*)d_out;
    // 48 planes * 32 row-groups * 128 col-groups = 196608 threads
    const int total_threads = 48 * 32 * 128;
    const int block = 256;
    const int grid = total_threads / block;    // 768 blocks
    median3x3_kernel<<<grid, block, 0, stream>>>(in, out);
}